// Round 5
// baseline (121.179 us; speedup 1.0000x reference)
//
#include <hip/hip_runtime.h>
#include <math.h>

#define BATCH    4
#define SEQLEN   2048
#define HIDDEN   1024
#define NMODES   32                  // N2 = STATE/2 complex modes
#define CHANNELS (BATCH * HIDDEN)    // 4096
#define LPC      8                   // lanes per channel
#define MPL      4                   // modes per lane (2 packed pairs)
#define CHBLK    (CHANNELS / 32)     // 128 channel-blocks (32 channels/block)

typedef float f2 __attribute__((ext_vector_type(2)));

// Packed fp32 math (full-rate on CDNA). Inline asm so it cannot scalarize.
__device__ __forceinline__ f2 pk_fma(f2 a, f2 b, f2 c) {
    f2 d;
    asm("v_pk_fma_f32 %0, %1, %2, %3" : "=v"(d) : "v"(a), "v"(b), "v"(c));
    return d;
}
__device__ __forceinline__ f2 pk_mul(f2 a, f2 b) {
    f2 d;
    asm("v_pk_mul_f32 %0, %1, %2" : "=v"(d) : "v"(a), "v"(b));
    return d;
}

// DPP cross-lane adds (VALU-only). 8-lane sum: xor1, xor2, half-mirror.
template <int CTRL>
__device__ __forceinline__ float dpp_add(float p) {
    int t = __builtin_amdgcn_update_dpp(0, __float_as_int(p), CTRL, 0xF, 0xF, true);
    return p + __int_as_float(t);
}
__device__ __forceinline__ float sum8(float p) {
    p = dpp_add<0xB1>(p);    // quad_perm xor1
    p = dpp_add<0x4E>(p);    // quad_perm xor2
    p = dpp_add<0x141>(p);   // row_half_mirror: pairs the two quads per 8 lanes
    return p;
}

// Bilinear (GBT alpha=0.5) discretization for one mode.
__device__ __forceinline__ void mode_coef(
    float dt, float al, float aim, float br_in, float bi_in,
    float& adr, float& adi, float& bdr, float& bdi)
{
    const float hd = 0.5f * dt;
    const float ar = -expf(al);
    const float dr = 1.0f - hd * ar;
    const float di = -hd * aim;
    const float inv = 1.0f / (dr * dr + di * di);
    const float nr = 1.0f + hd * ar;
    const float ni = hd * aim;
    adr = (nr * dr + ni * di) * inv;
    adi = (ni * dr - nr * di) * inv;
    const float tbr = dt * br_in, tbi = dt * bi_in;
    bdr = (tbr * dr + tbi * di) * inv;
    bdi = (tbi * dr - tbr * di) * inv;
}

__device__ __forceinline__ void load_coefs4(
    const float* __restrict__ log_dt, const float* __restrict__ A_log,
    const float* __restrict__ A_imag, const float* __restrict__ Bp,
    int h, int ll,
    float adr[4], float adi[4], float bdr[4], float bdi[4])
{
    const int m0 = ll * MPL;
    const float dt = expf(log_dt[h]);
    const float4 al  = *(const float4*)(A_log  + (size_t)h * NMODES + m0);
    const float4 am  = *(const float4*)(A_imag + (size_t)h * NMODES + m0);
    const float4 b01 = *(const float4*)(Bp + ((size_t)h * NMODES + m0) * 2);
    const float4 b23 = *(const float4*)(Bp + ((size_t)h * NMODES + m0) * 2 + 4);
    mode_coef(dt, al.x, am.x, b01.x, b01.y, adr[0], adi[0], bdr[0], bdi[0]);
    mode_coef(dt, al.y, am.y, b01.z, b01.w, adr[1], adi[1], bdr[1], bdi[1]);
    mode_coef(dt, al.z, am.z, b23.x, b23.y, adr[2], adi[2], bdr[2], bdi[2]);
    mode_coef(dt, al.w, am.w, b23.z, b23.w, adr[3], adi[3], bdr[3], bdi[3]);
}

// ---- Kernel 1: chunk-local end states from x=0, chunks 0..NC-2 -----------
// Block = 256 thr = 32 channels (8 lanes/channel, 4 modes/lane).
template <int NC>
__global__ void ssm_chunk_states(
    const float* __restrict__ input,
    const float* __restrict__ log_dt,
    const float* __restrict__ A_log,
    const float* __restrict__ A_imag,
    const float* __restrict__ Bp,
    float* __restrict__ states)          // [NC-1][CHANNELS][NMODES][2]
{
    constexpr int CL = SEQLEN / NC;
    const int tid   = threadIdx.x;
    const int g     = tid >> 3;
    const int ll    = tid & 7;
    const int chblk = blockIdx.x & (CHBLK - 1);
    const int chunk = blockIdx.x >> 7;             // 0..NC-2
    const int ch    = chblk * 32 + g;
    const int h     = ch & (HIDDEN - 1);
    const int b     = ch >> 10;

    const float* ip = input + ((size_t)b * SEQLEN + (size_t)chunk * CL) * HIDDEN + h;

    float ua[8], ub[8];
    #pragma unroll
    for (int j = 0; j < 8; ++j) ua[j] = ip[(size_t)j * HIDDEN];

    float adr[4], adi[4], bdr[4], bdi[4];
    load_coefs4(log_dt, A_log, A_imag, Bp, h, ll, adr, adi, bdr, bdi);

    const f2 adr0 = {adr[0], adr[1]}, adr1 = {adr[2], adr[3]};
    const f2 adi0 = {adi[0], adi[1]}, adi1 = {adi[2], adi[3]};
    const f2 nad0 = {-adi[0], -adi[1]}, nad1 = {-adi[2], -adi[3]};
    const f2 br0  = {bdr[0], bdr[1]}, br1 = {bdr[2], bdr[3]};
    const f2 bi0  = {bdi[0], bdi[1]}, bi1 = {bdi[2], bdi[3]};

    f2 vr0 = {0.f, 0.f}, vi0 = {0.f, 0.f}, vr1 = {0.f, 0.f}, vi1 = {0.f, 0.f};

    #pragma unroll 1
    for (int t0 = 0; t0 < CL; t0 += 16) {
        #pragma unroll
        for (int j = 0; j < 8; ++j) ub[j] = ip[(size_t)(t0 + 8 + j) * HIDDEN];
        #pragma unroll
        for (int j = 0; j < 8; ++j) {
            f2 u2; u2.x = ua[j]; u2.y = ua[j];
            const f2 nvr0 = pk_fma(adr0, vr0, pk_fma(nad0, vi0, pk_mul(br0, u2)));
            const f2 nvi0 = pk_fma(adi0, vr0, pk_fma(adr0, vi0, pk_mul(bi0, u2)));
            const f2 nvr1 = pk_fma(adr1, vr1, pk_fma(nad1, vi1, pk_mul(br1, u2)));
            const f2 nvi1 = pk_fma(adi1, vr1, pk_fma(adr1, vi1, pk_mul(bi1, u2)));
            vr0 = nvr0; vi0 = nvi0; vr1 = nvr1; vi1 = nvi1;
        }
        if (t0 + 16 < CL) {
            #pragma unroll
            for (int j = 0; j < 8; ++j) ua[j] = ip[(size_t)(t0 + 16 + j) * HIDDEN];
        }
        #pragma unroll
        for (int j = 0; j < 8; ++j) {
            f2 u2; u2.x = ub[j]; u2.y = ub[j];
            const f2 nvr0 = pk_fma(adr0, vr0, pk_fma(nad0, vi0, pk_mul(br0, u2)));
            const f2 nvi0 = pk_fma(adi0, vr0, pk_fma(adr0, vi0, pk_mul(bi0, u2)));
            const f2 nvr1 = pk_fma(adr1, vr1, pk_fma(nad1, vi1, pk_mul(br1, u2)));
            const f2 nvi1 = pk_fma(adi1, vr1, pk_fma(adr1, vi1, pk_mul(bi1, u2)));
            vr0 = nvr0; vi0 = nvi0; vr1 = nvr1; vi1 = nvi1;
        }
    }

    float* sp = states + (((size_t)chunk * CHANNELS + ch) * NMODES + ll * MPL) * 2;
    *(float4*)(sp)     = make_float4(vr0.x, vi0.x, vr0.y, vi0.y);
    *(float4*)(sp + 4) = make_float4(vr1.x, vi1.x, vr1.y, vi1.y);
}

// ---- Kernel 2: full scan per chunk with reconstructed init, writes y -----
template <int NC>
__global__ void ssm_chunk_scan(
    const float* __restrict__ input,
    const float* __restrict__ log_dt,
    const float* __restrict__ Dp,
    const float* __restrict__ A_log,
    const float* __restrict__ A_imag,
    const float* __restrict__ Bp,
    const float* __restrict__ Cp,
    const float* __restrict__ states,
    float* __restrict__ out)
{
    constexpr int CL     = SEQLEN / NC;
    constexpr int LOG2CL = (CL == 64) ? 6 : (CL == 128) ? 7 : 8;
    const int tid   = threadIdx.x;
    const int g     = tid >> 3;
    const int ll    = tid & 7;
    const int chblk = blockIdx.x & (CHBLK - 1);
    const int chunk = blockIdx.x >> 7;             // 0..NC-1
    const int ch    = chblk * 32 + g;
    const int h     = ch & (HIDDEN - 1);
    const int b     = ch >> 10;
    const int m0    = ll * MPL;

    const float* ip = input + ((size_t)b * SEQLEN + (size_t)chunk * CL) * HIDDEN + h;
    float*       op = out   + ((size_t)b * SEQLEN + (size_t)chunk * CL) * HIDDEN + h;

    float ua[8], ub[8];
    #pragma unroll
    for (int j = 0; j < 8; ++j) ua[j] = ip[(size_t)j * HIDDEN];

    float adr[4], adi[4], bdr[4], bdi[4];
    load_coefs4(log_dt, A_log, A_imag, Bp, h, ll, adr, adi, bdr, bdi);

    // Cc = 2*(C0 + i C1); fold into B' = Cc .* B_disc
    const float4 c01 = *(const float4*)(Cp + ((size_t)h * NMODES + m0) * 2);
    const float4 c23 = *(const float4*)(Cp + ((size_t)h * NMODES + m0) * 2 + 4);
    float cr[4], ci[4], bpr[4], bpi[4];
    cr[0] = 2.f * c01.x; ci[0] = 2.f * c01.y;
    cr[1] = 2.f * c01.z; ci[1] = 2.f * c01.w;
    cr[2] = 2.f * c23.x; ci[2] = 2.f * c23.y;
    cr[3] = 2.f * c23.z; ci[3] = 2.f * c23.w;
    #pragma unroll
    for (int k = 0; k < 4; ++k) {
        bpr[k] = cr[k] * bdr[k] - ci[k] * bdi[k];
        bpi[k] = cr[k] * bdi[k] + ci[k] * bdr[k];
    }

    // Apow = A_disc^CL by repeated squaring
    float pr[4], pi[4];
    #pragma unroll
    for (int k = 0; k < 4; ++k) { pr[k] = adr[k]; pi[k] = adi[k]; }
    #pragma unroll
    for (int s = 0; s < LOG2CL; ++s) {
        #pragma unroll
        for (int k = 0; k < 4; ++k) {
            const float npr = pr[k] * pr[k] - pi[k] * pi[k];
            const float npi = 2.f * pr[k] * pi[k];
            pr[k] = npr; pi[k] = npi;
        }
    }

    // True chunk-start state via Horner over previous chunk-end states
    float Xr[4] = {0.f, 0.f, 0.f, 0.f}, Xi[4] = {0.f, 0.f, 0.f, 0.f};
    for (int c2 = 0; c2 < chunk; ++c2) {
        const float* sp = states + (((size_t)c2 * CHANNELS + ch) * NMODES + m0) * 2;
        const float4 sa = *(const float4*)(sp);
        const float4 sb = *(const float4*)(sp + 4);
        const float srr[4] = {sa.x, sa.z, sb.x, sb.z};
        const float sii[4] = {sa.y, sa.w, sb.y, sb.w};
        #pragma unroll
        for (int k = 0; k < 4; ++k) {
            const float nXr = fmaf(pr[k], Xr[k], fmaf(-pi[k], Xi[k], srr[k]));
            const float nXi = fmaf(pi[k], Xr[k], fmaf( pr[k], Xi[k], sii[k]));
            Xr[k] = nXr; Xi[k] = nXi;
        }
    }

    // v = Cc .* X  (fold C into the running state)
    float vrs[4], vis[4];
    #pragma unroll
    for (int k = 0; k < 4; ++k) {
        vrs[k] = cr[k] * Xr[k] - ci[k] * Xi[k];
        vis[k] = cr[k] * Xi[k] + ci[k] * Xr[k];
    }

    const f2 adr0 = {adr[0], adr[1]}, adr1 = {adr[2], adr[3]};
    const f2 adi0 = {adi[0], adi[1]}, adi1 = {adi[2], adi[3]};
    const f2 nad0 = {-adi[0], -adi[1]}, nad1 = {-adi[2], -adi[3]};
    const f2 br0  = {bpr[0], bpr[1]}, br1 = {bpr[2], bpr[3]};
    const f2 bi0  = {bpi[0], bpi[1]}, bi1 = {bpi[2], bpi[3]};
    f2 vr0 = {vrs[0], vrs[1]}, vr1 = {vrs[2], vrs[3]};
    f2 vi0 = {vis[0], vis[1]}, vi1 = {vis[2], vis[3]};

    const float Dh = Dp[h];
    const bool writer = (ll == 0);

    #pragma unroll 1
    for (int t0 = 0; t0 < CL; t0 += 16) {
        #pragma unroll
        for (int j = 0; j < 8; ++j) ub[j] = ip[(size_t)(t0 + 8 + j) * HIDDEN];
        #pragma unroll
        for (int j = 0; j < 8; ++j) {
            const float uu = ua[j];
            f2 u2; u2.x = uu; u2.y = uu;
            const f2 nvr0 = pk_fma(adr0, vr0, pk_fma(nad0, vi0, pk_mul(br0, u2)));
            const f2 nvi0 = pk_fma(adi0, vr0, pk_fma(adr0, vi0, pk_mul(bi0, u2)));
            const f2 nvr1 = pk_fma(adr1, vr1, pk_fma(nad1, vi1, pk_mul(br1, u2)));
            const f2 nvi1 = pk_fma(adi1, vr1, pk_fma(adr1, vi1, pk_mul(bi1, u2)));
            vr0 = nvr0; vi0 = nvi0; vr1 = nvr1; vi1 = nvi1;
            const f2 s2 = vr0 + vr1;
            float p = s2.x + s2.y;
            p = sum8(p);
            if (writer) op[(size_t)(t0 + j) * HIDDEN] = fmaf(Dh, uu, p);
        }
        if (t0 + 16 < CL) {
            #pragma unroll
            for (int j = 0; j < 8; ++j) ua[j] = ip[(size_t)(t0 + 16 + j) * HIDDEN];
        }
        #pragma unroll
        for (int j = 0; j < 8; ++j) {
            const float uu = ub[j];
            f2 u2; u2.x = uu; u2.y = uu;
            const f2 nvr0 = pk_fma(adr0, vr0, pk_fma(nad0, vi0, pk_mul(br0, u2)));
            const f2 nvi0 = pk_fma(adi0, vr0, pk_fma(adr0, vi0, pk_mul(bi0, u2)));
            const f2 nvr1 = pk_fma(adr1, vr1, pk_fma(nad1, vi1, pk_mul(br1, u2)));
            const f2 nvi1 = pk_fma(adi1, vr1, pk_fma(adr1, vi1, pk_mul(bi1, u2)));
            vr0 = nvr0; vi0 = nvi0; vr1 = nvr1; vi1 = nvi1;
            const f2 s2 = vr0 + vr1;
            float p = s2.x + s2.y;
            p = sum8(p);
            if (writer) op[(size_t)(t0 + 8 + j) * HIDDEN] = fmaf(Dh, uu, p);
        }
    }
}

template <int NC>
static void launch_nc(const float* input, const float* log_dt, const float* Dp,
                      const float* A_log, const float* A_imag, const float* Bp,
                      const float* Cp, float* states, float* out,
                      hipStream_t stream) {
    {
        dim3 grid(CHBLK * (NC - 1)), block(256);
        ssm_chunk_states<NC><<<grid, block, 0, stream>>>(
            input, log_dt, A_log, A_imag, Bp, states);
    }
    {
        dim3 grid(CHBLK * NC), block(256);
        ssm_chunk_scan<NC><<<grid, block, 0, stream>>>(
            input, log_dt, Dp, A_log, A_imag, Bp, Cp, states, out);
    }
}

extern "C" void kernel_launch(void* const* d_in, const int* in_sizes, int n_in,
                              void* d_out, int out_size, void* d_ws, size_t ws_size,
                              hipStream_t stream) {
    const float* input  = (const float*)d_in[0];
    const float* log_dt = (const float*)d_in[1];
    const float* Dp     = (const float*)d_in[2];
    const float* A_log  = (const float*)d_in[3];
    const float* A_imag = (const float*)d_in[4];
    const float* Bp     = (const float*)d_in[5];
    const float* Cp     = (const float*)d_in[6];
    float* out    = (float*)d_out;
    float* states = (float*)d_ws;

    auto need = [](int nc) {
        return (size_t)(nc - 1) * CHANNELS * NMODES * 2 * sizeof(float);
    };
    if (ws_size >= need(32))
        launch_nc<32>(input, log_dt, Dp, A_log, A_imag, Bp, Cp, states, out, stream);
    else if (ws_size >= need(16))
        launch_nc<16>(input, log_dt, Dp, A_log, A_imag, Bp, Cp, states, out, stream);
    else
        launch_nc<8>(input, log_dt, Dp, A_log, A_imag, Bp, Cp, states, out, stream);
}